// Round 1
// baseline (13755.925 us; speedup 1.0000x reference)
//
#include <hip/hip_runtime.h>
#include <stdint.h>

#define F_DIM 512
#define CAP   64
#define MAXV  9216

typedef unsigned long long u64;

// ---------------- per-vertex squared norm (fp64 accumulate) ----------------
__global__ void k_sq(const float* __restrict__ img, double* __restrict__ sqd, int V) {
  int v = blockIdx.x;
  if (v >= V) return;
  const float* row = img + (size_t)v * F_DIM;
  double s = 0.0;
  for (int f = threadIdx.x; f < F_DIM; f += 64) {
    double x = (double)row[f];
    s += x * x;
  }
  for (int off = 32; off > 0; off >>= 1) s += __shfl_down(s, off);
  if (threadIdx.x == 0) sqd[v] = s;
}

// ---------------- zero degrees + edge eligibility (boundary test) ----------
__global__ void k_prep(const float* __restrict__ vs, const int* __restrict__ edges,
                       int V, int E, int* __restrict__ deg, unsigned char* __restrict__ elig) {
  int i = blockIdx.x * blockDim.x + threadIdx.x;
  if (i < V) deg[i] = 0;
  if (i < E) {
    int a = edges[i], b = edges[E + i];
    float ax = vs[2 * a], ay = vs[2 * a + 1];
    float bx = vs[2 * b], by = vs[2 * b + 1];
    const float eps = 1e-3f;
    const float hi = 1.0f - 1e-3f;
    bool ba = (ax < eps) || (ax > hi) || (ay < eps) || (ay > hi);
    bool bb = (bx < eps) || (bx > hi) || (by < eps) || (by > hi);
    elig[i] = (!ba && !bb) ? 1 : 0;
  }
}

// ---------------- build neighbor lists -------------------------------------
__global__ void k_lists(const int* __restrict__ edges, int E,
                        int* __restrict__ deg, unsigned short* __restrict__ nbr) {
  int e = blockIdx.x * blockDim.x + threadIdx.x;
  if (e >= E) return;
  int a = edges[e], b = edges[E + e];
  int ia = atomicAdd(&deg[a], 1);
  nbr[a * CAP + ia] = (unsigned short)b;
  int ib = atomicAdd(&deg[b], 1);
  nbr[b * CAP + ib] = (unsigned short)a;
}

// ---------------- sortable keys: prio(double) top bits | edge id -----------
__global__ void k_keys(const double* __restrict__ sqd, const int* __restrict__ edges,
                       int E, int P, u64* __restrict__ keys) {
  int e = blockIdx.x * blockDim.x + threadIdx.x;
  if (e >= P) return;
  if (e < E) {
    double prio = sqd[edges[e]] + sqd[edges[E + e]];
    u64 bits = (u64)__double_as_longlong(prio);  // prio > 0 -> bits monotone
    keys[e] = (bits & ~0xFFFFull) | (u64)e;
  } else {
    keys[e] = ~0ull;
  }
}

// ---------------- single-block bitonic sort (P = pow2) ---------------------
__global__ void k_sort(u64* __restrict__ keys, int n) {
  int tid = threadIdx.x;
  int nt = blockDim.x;
  for (int k = 2; k <= n; k <<= 1) {
    for (int j = k >> 1; j > 0; j >>= 1) {
      for (int i = tid; i < n; i += nt) {
        int ixj = i ^ j;
        if (ixj > i) {
          u64 x = keys[i], y = keys[ixj];
          bool up = ((i & k) == 0);
          if (up ? (x > y) : (x < y)) { keys[i] = y; keys[ixj] = x; }
        }
      }
      __syncthreads();
    }
  }
}

// ---------------- sequential greedy decimation (single wave) ---------------
__global__ void __launch_bounds__(64)
k_decimate(const int* __restrict__ edges, int E, int V, int target,
           const u64* __restrict__ keys, const unsigned char* __restrict__ elig,
           const int* __restrict__ deg_g, unsigned short* __restrict__ nbr,
           int2* __restrict__ events, int* __restrict__ nev_out) {
  __shared__ unsigned short degs[MAXV];
  __shared__ unsigned char alives[MAXV];
  int lane = threadIdx.x;
  if (V > MAXV) return;
  for (int v = lane; v < V; v += 64) { degs[v] = (unsigned short)deg_g[v]; alives[v] = 1; }
  __syncthreads();

  int count = V, ptr = 0, nev = 0;
  int base = -64;
  int me0 = 0, me1 = 0, mel = 0;

  while (count > target && ptr < E) {
    if (ptr - base >= 64) {                 // refill prefetch batch
      base = ptr;
      int t = base + lane;
      u64 kk = (t < E) ? keys[t] : ~0ull;
      int myeid = (int)(kk & 0xFFFF);
      if (t < E) { me0 = edges[myeid]; me1 = edges[E + myeid]; mel = elig[myeid]; }
      else       { me0 = 0; me1 = 0; mel = 0; }
    }
    int idx = ptr - base;
    ptr++;
    int v0 = __shfl(me0, idx);
    int v1 = __shfl(me1, idx);
    int el = __shfl(mel, idx);
    if (!el) continue;
    if (!alives[v0] || !alives[v1]) continue;

    int d0 = degs[v0], d1 = degs[v1];
    unsigned aa = (lane < d0) ? (unsigned)nbr[v0 * CAP + lane] : 0x10000u;
    unsigned bb = (lane < d1) ? (unsigned)nbr[v1 * CAP + lane] : 0x20000u;
    bool aInB = false, bInA = false;
    int dmax = d0 > d1 ? d0 : d1;
    for (int j = 0; j < dmax; ++j) {
      unsigned aj = __shfl(aa, j);
      unsigned bj = __shfl(bb, j);
      aInB = aInB || (aa == bj);
      bInA = bInA || (bb == aj);
    }
    int common = __popcll(__ballot(aInB));
    if (common != 2) continue;

    // ---- merge v1 -> v0 ----
    u64 keepMask = __ballot(lane < d0 && aa != (unsigned)v1);
    u64 addMask  = __ballot(lane < d1 && bb != (unsigned)v0 && !bInA);
    int nKeep = __popcll(keepMask);
    int nAdd  = __popcll(addMask);
    int newd  = nKeep + nAdd; if (newd > CAP) newd = CAP;
    u64 below = (lane == 0) ? 0ull : (~0ull >> (64 - lane));
    if (keepMask & (1ull << lane)) {
      int pos = __popcll(keepMask & below);
      nbr[v0 * CAP + pos] = (unsigned short)aa;
    }
    if (addMask & (1ull << lane)) {
      int pos = nKeep + __popcll(addMask & below);
      if (pos < CAP) nbr[v0 * CAP + pos] = (unsigned short)bb;
    }
    // update neighbors u of v1 (u != v0): replace v1 by v0, or drop v1 if v0 present
    bool doU = (lane < d1) && (bb != (unsigned)v0);
    if (doU) {
      int u = (int)bb;
      int du = degs[u];
      int posv1 = -1;
      for (int i2 = 0; i2 < du; ++i2) {
        if ((unsigned)nbr[u * CAP + i2] == (unsigned)v1) posv1 = i2;
      }
      if (posv1 >= 0) {
        if (bInA) {  // v0 already a neighbor of u: remove v1
          nbr[u * CAP + posv1] = nbr[u * CAP + du - 1];
          degs[u] = (unsigned short)(du - 1);
        } else {
          nbr[u * CAP + posv1] = (unsigned short)v0;
        }
      }
    }
    if (lane == 0) {
      degs[v0] = (unsigned short)newd;
      degs[v1] = 0;
      alives[v1] = 0;
      events[nev] = make_int2(v0, v1);
    }
    nev++;
    count--;
  }
  if (lane == 0) nev_out[0] = nev;
}

// ---------------- reverse-replay: owner + weight per original vertex -------
__global__ void k_weights(const int2* __restrict__ events, const int* __restrict__ nev_p,
                          int V, int* __restrict__ own, float* __restrict__ wgt) {
  __shared__ int O[MAXV];
  __shared__ unsigned short H[MAXV];
  int tid = threadIdx.x;
  if (V > MAXV) return;
  for (int v = tid; v < V; v += blockDim.x) { O[v] = v; H[v] = 0; }
  __syncthreads();
  if (tid == 0) {
    int n = nev_p[0];
    for (int k = n - 1; k >= 0; --k) {
      int2 ev = events[k];
      int h = (int)H[ev.x] + 1;
      H[ev.x] = (unsigned short)h;
      H[ev.y] = (unsigned short)h;
      O[ev.y] = O[ev.x];
    }
  }
  __syncthreads();
  for (int v = tid; v < V; v += blockDim.x) {
    own[v] = O[v];
    wgt[v] = ldexpf(1.0f, -(int)H[v]);
  }
}

// ---------------- output ---------------------------------------------------
__global__ void k_zero(float4* __restrict__ out, int n4) {
  int i = blockIdx.x * blockDim.x + threadIdx.x;
  if (i < n4) out[i] = make_float4(0.f, 0.f, 0.f, 0.f);
}

__global__ void k_scatter(const float* __restrict__ img, const int* __restrict__ own,
                          const float* __restrict__ wgt, float* __restrict__ out, int V) {
  int v = blockIdx.x;
  if (v >= V) return;
  float w = wgt[v];
  int o = own[v];
  const float* src = img + (size_t)v * F_DIM;
  float* dst = out + (size_t)o * F_DIM;
  if (w == 1.0f) {
    // h==0 => v never touched by any event => sole contributor to its own row
    for (int f = threadIdx.x; f < F_DIM; f += blockDim.x) dst[f] = src[f];
  } else {
    for (int f = threadIdx.x; f < F_DIM; f += blockDim.x) atomicAdd(&dst[f], w * src[f]);
  }
}

extern "C" void kernel_launch(void* const* d_in, const int* in_sizes, int n_in,
                              void* d_out, int out_size, void* d_ws, size_t ws_size,
                              hipStream_t stream) {
  const float* img  = (const float*)d_in[0];
  const int* edges  = (const int*)d_in[1];
  const float* vs   = (const float*)d_in[2];
  int V = in_sizes[2] / 2;
  int E = in_sizes[1] / 2;
  int P = 1; while (P < E) P <<= 1;

  char* wsp = (char*)d_ws;
  size_t off = 0;
  auto alloc = [&](size_t bytes) -> void* {
    void* p = (void*)(wsp + off);
    off = (off + bytes + 255) & ~(size_t)255;
    return p;
  };
  double* sqd          = (double*)alloc((size_t)V * 8);
  u64* keys            = (u64*)alloc((size_t)P * 8);
  int* deg             = (int*)alloc((size_t)V * 4);
  unsigned short* nbr  = (unsigned short*)alloc((size_t)V * CAP * 2);
  unsigned char* elig  = (unsigned char*)alloc((size_t)E);
  int2* events         = (int2*)alloc((size_t)(V / 2 + 64) * 8);
  int* nev             = (int*)alloc(256);
  int* own             = (int*)alloc((size_t)V * 4);
  float* wgt           = (float*)alloc((size_t)V * 4);

  hipLaunchKernelGGL(k_sq, dim3(V), dim3(64), 0, stream, img, sqd, V);
  int mx = V > E ? V : E;
  hipLaunchKernelGGL(k_prep, dim3((mx + 255) / 256), dim3(256), 0, stream, vs, edges, V, E, deg, elig);
  hipLaunchKernelGGL(k_lists, dim3((E + 255) / 256), dim3(256), 0, stream, edges, E, deg, nbr);
  hipLaunchKernelGGL(k_keys, dim3((P + 255) / 256), dim3(256), 0, stream, sqd, edges, E, P, keys);
  hipLaunchKernelGGL(k_sort, dim3(1), dim3(1024), 0, stream, keys, P);
  hipLaunchKernelGGL(k_decimate, dim3(1), dim3(64), 0, stream,
                     edges, E, V, V / 2, keys, elig, deg, nbr, events, nev);
  hipLaunchKernelGGL(k_weights, dim3(1), dim3(256), 0, stream, events, nev, V, own, wgt);
  int n4 = (V * F_DIM) / 4;
  hipLaunchKernelGGL(k_zero, dim3((n4 + 255) / 256), dim3(256), 0, stream, (float4*)d_out, n4);
  hipLaunchKernelGGL(k_scatter, dim3(V), dim3(256), 0, stream, img, own, wgt, (float*)d_out, V);
}

// Round 2
// 11559.203 us; speedup vs baseline: 1.1900x; 1.1900x over previous
//
#include <hip/hip_runtime.h>
#include <stdint.h>

#define F_DIM 512
#define CAP   64
#define MAXV  9216

typedef unsigned long long u64;

// ---------------- per-vertex squared norm (fp64 accumulate) ----------------
__global__ void k_sq(const float* __restrict__ img, double* __restrict__ sqd, int V) {
  int v = blockIdx.x;
  if (v >= V) return;
  const float* row = img + (size_t)v * F_DIM;
  double s = 0.0;
  for (int f = threadIdx.x; f < F_DIM; f += 64) {
    double x = (double)row[f];
    s += x * x;
  }
  for (int off = 32; off > 0; off >>= 1) s += __shfl_down(s, off);
  if (threadIdx.x == 0) sqd[v] = s;
}

// ---------------- zero degrees + edge eligibility (boundary test) ----------
__global__ void k_prep(const float* __restrict__ vs, const int* __restrict__ edges,
                       int V, int E, int* __restrict__ deg, unsigned char* __restrict__ elig) {
  int i = blockIdx.x * blockDim.x + threadIdx.x;
  if (i < V) deg[i] = 0;
  if (i < E) {
    int a = edges[i], b = edges[E + i];
    float ax = vs[2 * a], ay = vs[2 * a + 1];
    float bx = vs[2 * b], by = vs[2 * b + 1];
    const float eps = 1e-3f;
    const float hi = 1.0f - 1e-3f;
    bool ba = (ax < eps) || (ax > hi) || (ay < eps) || (ay > hi);
    bool bb = (bx < eps) || (bx > hi) || (by < eps) || (by > hi);
    elig[i] = (!ba && !bb) ? 1 : 0;
  }
}

// ---------------- build neighbor lists -------------------------------------
__global__ void k_lists(const int* __restrict__ edges, int E,
                        int* __restrict__ deg, unsigned short* __restrict__ nbr) {
  int e = blockIdx.x * blockDim.x + threadIdx.x;
  if (e >= E) return;
  int a = edges[e], b = edges[E + e];
  int ia = atomicAdd(&deg[a], 1);
  nbr[a * CAP + ia] = (unsigned short)b;
  int ib = atomicAdd(&deg[b], 1);
  nbr[b * CAP + ib] = (unsigned short)a;
}

// ---------------- sortable keys: prio(double) top bits | edge id -----------
__global__ void k_keys(const double* __restrict__ sqd, const int* __restrict__ edges,
                       int E, int P, u64* __restrict__ keys) {
  int e = blockIdx.x * blockDim.x + threadIdx.x;
  if (e >= P) return;
  if (e < E) {
    double prio = sqd[edges[e]] + sqd[edges[E + e]];
    u64 bits = (u64)__double_as_longlong(prio);  // prio > 0 -> bits monotone
    keys[e] = (bits & ~0xFFFFull) | (u64)e;
  } else {
    keys[e] = ~0ull;
  }
}

// ---------------- single-block bitonic sort (P = pow2) ---------------------
__global__ void k_sort(u64* __restrict__ keys, int n) {
  int tid = threadIdx.x;
  int nt = blockDim.x;
  for (int k = 2; k <= n; k <<= 1) {
    for (int j = k >> 1; j > 0; j >>= 1) {
      for (int i = tid; i < n; i += nt) {
        int ixj = i ^ j;
        if (ixj > i) {
          u64 x = keys[i], y = keys[ixj];
          bool up = ((i & k) == 0);
          if (up ? (x > y) : (x < y)) { keys[i] = y; keys[ixj] = x; }
        }
      }
      __syncthreads();
    }
  }
}

// ---------------- gather sorted (v0,v1,elig) into one packed word ----------
__global__ void k_reorder(const u64* __restrict__ keys, const int* __restrict__ edges,
                          const unsigned char* __restrict__ elig, int E,
                          unsigned* __restrict__ packed) {
  int t = blockIdx.x * blockDim.x + threadIdx.x;
  if (t >= E) return;
  int eid = (int)(keys[t] & 0xFFFFull);
  unsigned v0 = (unsigned)edges[eid];
  unsigned v1 = (unsigned)edges[E + eid];
  unsigned el = (unsigned)elig[eid];
  packed[t] = v0 | (v1 << 14) | (el << 28);
}

// ---------------- sequential greedy decimation (single wave) ---------------
__global__ void __launch_bounds__(64)
k_decimate(int E, int V, int target, const unsigned* __restrict__ packed,
           const int* __restrict__ deg_g, unsigned short* __restrict__ nbr,
           int2* __restrict__ events, int* __restrict__ nev_out) {
  __shared__ unsigned short degs[MAXV];
  int lane = threadIdx.x;
  if (V > MAXV) return;
  for (int v = lane; v < V; v += 64) degs[v] = (unsigned short)deg_g[v];
  __syncthreads();

  int count = V, nev = 0;
  bool stop = false;

  for (int base = 0; base < E && !stop; base += 64) {
    int t = base + lane;
    unsigned pk = (t < E) ? packed[t] : 0u;
    int mv0 = (int)(pk & 0x3FFFu);
    int mv1 = (int)((pk >> 14) & 0x3FFFu);
    bool cand = (t < E) && ((pk >> 28) & 1u) && (degs[mv0] > 0) && (degs[mv1] > 0);
    u64 cm = __ballot(cand);

    while (cm) {
      int idx = __builtin_ctzll(cm);
      cm &= cm - 1;
      int cv0 = __shfl(mv0, idx);
      int cv1 = __shfl(mv1, idx);

      // issue row gathers immediately (unmasked); LDS recheck overlaps latency
      unsigned aar = (unsigned)nbr[cv0 * CAP + lane];
      unsigned bbr = (unsigned)nbr[cv1 * CAP + lane];
      int d0 = degs[cv0], d1 = degs[cv1];
      if (d0 == 0 || d1 == 0) continue;   // died earlier in this batch

      unsigned aa = (lane < d0) ? aar : 0x10000u;
      unsigned bb = (lane < d1) ? bbr : 0x20000u;

      // |N(v0) & N(v1)| via: does my aa appear among the bb's?
      bool aInB = false;
      for (int j = 0; j < d1; ++j) {
        unsigned bj = __shfl(bb, j);
        aInB = aInB || (aa == bj);
      }
      if (__popcll(__ballot(aInB)) != 2) continue;

      // need bInA only for accepted merges
      bool bInA = false;
      for (int j = 0; j < d0; ++j) {
        unsigned aj = __shfl(aa, j);
        bInA = bInA || (bb == aj);
      }

      // ---- merge cv1 -> cv0 ----
      u64 keepMask = __ballot(lane < d0 && aa != (unsigned)cv1);
      u64 addMask  = __ballot(lane < d1 && bb != (unsigned)cv0 && !bInA);
      int nKeep = __popcll(keepMask);
      int newd  = nKeep + __popcll(addMask);
      if (newd > CAP) newd = CAP;
      u64 below = (lane == 0) ? 0ull : (~0ull >> (64 - lane));
      if (keepMask & (1ull << lane)) {
        int pos = __popcll(keepMask & below);
        nbr[cv0 * CAP + pos] = (unsigned short)aa;
      }
      if (addMask & (1ull << lane)) {
        int pos = nKeep + __popcll(addMask & below);
        if (pos < CAP) nbr[cv0 * CAP + pos] = (unsigned short)bb;
      }

      // update each u in N(v1)\{v0}: replace v1 by v0, or drop v1 if v0 already there
      bool doU = (lane < d1) && (bb != (unsigned)cv0);
      if (doU) {
        int u = (int)bb;
        int du = degs[u];
        const uint4* rowp = (const uint4*)(nbr + u * CAP);
        unsigned tg = (unsigned)cv1;
        int posv1 = -1;
        int nw = (du + 7) >> 3;
        for (int c = 0; c < nw; ++c) {
          uint4 w = rowp[c];
          int b8 = c << 3;
          if ((w.x & 0xFFFFu) == tg && b8 + 0 < du) posv1 = b8 + 0;
          if ((w.x >> 16)     == tg && b8 + 1 < du) posv1 = b8 + 1;
          if ((w.y & 0xFFFFu) == tg && b8 + 2 < du) posv1 = b8 + 2;
          if ((w.y >> 16)     == tg && b8 + 3 < du) posv1 = b8 + 3;
          if ((w.z & 0xFFFFu) == tg && b8 + 4 < du) posv1 = b8 + 4;
          if ((w.z >> 16)     == tg && b8 + 5 < du) posv1 = b8 + 5;
          if ((w.w & 0xFFFFu) == tg && b8 + 6 < du) posv1 = b8 + 6;
          if ((w.w >> 16)     == tg && b8 + 7 < du) posv1 = b8 + 7;
        }
        if (posv1 >= 0) {
          if (bInA) {  // v0 already a neighbor of u: remove v1
            nbr[u * CAP + posv1] = nbr[u * CAP + du - 1];
            degs[u] = (unsigned short)(du - 1);
          } else {
            nbr[u * CAP + posv1] = (unsigned short)cv0;
          }
        }
      }
      if (lane == 0) {
        degs[cv0] = (unsigned short)newd;
        degs[cv1] = 0;
        events[nev] = make_int2(cv0, cv1);
      }
      // make all global/LDS updates visible before next candidate's loads
      asm volatile("s_waitcnt vmcnt(0) lgkmcnt(0)" ::: "memory");
      nev++;
      count--;
      if (count <= target) { stop = true; break; }
    }
  }
  if (lane == 0) nev_out[0] = nev;
}

// ---------------- reverse-replay: owner + weight per original vertex -------
__global__ void k_weights(const int2* __restrict__ events, const int* __restrict__ nev_p,
                          int V, int* __restrict__ own, float* __restrict__ wgt) {
  __shared__ int O[MAXV];
  __shared__ unsigned short H[MAXV];
  int tid = threadIdx.x;
  if (V > MAXV) return;
  for (int v = tid; v < V; v += blockDim.x) { O[v] = v; H[v] = 0; }
  __syncthreads();
  if (tid == 0) {
    int n = nev_p[0];
    for (int k = n - 1; k >= 0; --k) {
      int2 ev = events[k];
      int h = (int)H[ev.x] + 1;
      H[ev.x] = (unsigned short)h;
      H[ev.y] = (unsigned short)h;
      O[ev.y] = O[ev.x];
    }
  }
  __syncthreads();
  for (int v = tid; v < V; v += blockDim.x) {
    own[v] = O[v];
    wgt[v] = ldexpf(1.0f, -(int)H[v]);
  }
}

// ---------------- output ---------------------------------------------------
__global__ void k_zero(float4* __restrict__ out, int n4) {
  int i = blockIdx.x * blockDim.x + threadIdx.x;
  if (i < n4) out[i] = make_float4(0.f, 0.f, 0.f, 0.f);
}

__global__ void k_scatter(const float* __restrict__ img, const int* __restrict__ own,
                          const float* __restrict__ wgt, float* __restrict__ out, int V) {
  int v = blockIdx.x;
  if (v >= V) return;
  float w = wgt[v];
  int o = own[v];
  const float* src = img + (size_t)v * F_DIM;
  float* dst = out + (size_t)o * F_DIM;
  if (w == 1.0f) {
    for (int f = threadIdx.x; f < F_DIM; f += blockDim.x) dst[f] = src[f];
  } else {
    for (int f = threadIdx.x; f < F_DIM; f += blockDim.x) atomicAdd(&dst[f], w * src[f]);
  }
}

extern "C" void kernel_launch(void* const* d_in, const int* in_sizes, int n_in,
                              void* d_out, int out_size, void* d_ws, size_t ws_size,
                              hipStream_t stream) {
  const float* img  = (const float*)d_in[0];
  const int* edges  = (const int*)d_in[1];
  const float* vs   = (const float*)d_in[2];
  int V = in_sizes[2] / 2;
  int E = in_sizes[1] / 2;
  int P = 1; while (P < E) P <<= 1;

  char* wsp = (char*)d_ws;
  size_t off = 0;
  auto alloc = [&](size_t bytes) -> void* {
    void* p = (void*)(wsp + off);
    off = (off + bytes + 255) & ~(size_t)255;
    return p;
  };
  double* sqd          = (double*)alloc((size_t)V * 8);
  u64* keys            = (u64*)alloc((size_t)P * 8);
  int* deg             = (int*)alloc((size_t)V * 4);
  unsigned short* nbr  = (unsigned short*)alloc((size_t)V * CAP * 2);
  unsigned char* elig  = (unsigned char*)alloc((size_t)E);
  unsigned* packed     = (unsigned*)alloc((size_t)E * 4);
  int2* events         = (int2*)alloc((size_t)(V / 2 + 64) * 8);
  int* nev             = (int*)alloc(256);
  int* own             = (int*)alloc((size_t)V * 4);
  float* wgt           = (float*)alloc((size_t)V * 4);

  hipLaunchKernelGGL(k_sq, dim3(V), dim3(64), 0, stream, img, sqd, V);
  int mx = V > E ? V : E;
  hipLaunchKernelGGL(k_prep, dim3((mx + 255) / 256), dim3(256), 0, stream, vs, edges, V, E, deg, elig);
  hipLaunchKernelGGL(k_lists, dim3((E + 255) / 256), dim3(256), 0, stream, edges, E, deg, nbr);
  hipLaunchKernelGGL(k_keys, dim3((P + 255) / 256), dim3(256), 0, stream, sqd, edges, E, P, keys);
  hipLaunchKernelGGL(k_sort, dim3(1), dim3(1024), 0, stream, keys, P);
  hipLaunchKernelGGL(k_reorder, dim3((E + 255) / 256), dim3(256), 0, stream, keys, edges, elig, E, packed);
  hipLaunchKernelGGL(k_decimate, dim3(1), dim3(64), 0, stream,
                     E, V, V / 2, packed, deg, nbr, events, nev);
  hipLaunchKernelGGL(k_weights, dim3(1), dim3(256), 0, stream, events, nev, V, own, wgt);
  int n4 = (V * F_DIM) / 4;
  hipLaunchKernelGGL(k_zero, dim3((n4 + 255) / 256), dim3(256), 0, stream, (float4*)d_out, n4);
  hipLaunchKernelGGL(k_scatter, dim3(V), dim3(256), 0, stream, img, own, wgt, (float*)d_out, V);
}

// Round 3
// 8326.374 us; speedup vs baseline: 1.6521x; 1.3883x over previous
//
#include <hip/hip_runtime.h>
#include <stdint.h>

#define F_DIM 512
#define CAP   64
#define MAXV  9216

typedef unsigned long long u64;

// ---------------- per-vertex squared norm (fp64 accumulate) ----------------
__global__ void k_sq(const float* __restrict__ img, double* __restrict__ sqd, int V) {
  int v = blockIdx.x;
  if (v >= V) return;
  const float* row = img + (size_t)v * F_DIM;
  double s = 0.0;
  for (int f = threadIdx.x; f < F_DIM; f += 64) {
    double x = (double)row[f];
    s += x * x;
  }
  for (int off = 32; off > 0; off >>= 1) s += __shfl_down(s, off);
  if (threadIdx.x == 0) sqd[v] = s;
}

// ---------------- zero degrees + edge eligibility (boundary test) ----------
__global__ void k_prep(const float* __restrict__ vs, const int* __restrict__ edges,
                       int V, int E, int* __restrict__ deg, unsigned char* __restrict__ elig) {
  int i = blockIdx.x * blockDim.x + threadIdx.x;
  if (i < V) deg[i] = 0;
  if (i < E) {
    int a = edges[i], b = edges[E + i];
    float ax = vs[2 * a], ay = vs[2 * a + 1];
    float bx = vs[2 * b], by = vs[2 * b + 1];
    const float eps = 1e-3f;
    const float hi = 1.0f - 1e-3f;
    bool ba = (ax < eps) || (ax > hi) || (ay < eps) || (ay > hi);
    bool bb = (bx < eps) || (bx > hi) || (by < eps) || (by > hi);
    elig[i] = (!ba && !bb) ? 1 : 0;
  }
}

// ---------------- build neighbor lists -------------------------------------
__global__ void k_lists(const int* __restrict__ edges, int E,
                        int* __restrict__ deg, unsigned short* __restrict__ nbr) {
  int e = blockIdx.x * blockDim.x + threadIdx.x;
  if (e >= E) return;
  int a = edges[e], b = edges[E + e];
  int ia = atomicAdd(&deg[a], 1);
  nbr[a * CAP + ia] = (unsigned short)b;
  int ib = atomicAdd(&deg[b], 1);
  nbr[b * CAP + ib] = (unsigned short)a;
}

// ---------------- sortable keys: prio(double) top bits | edge id -----------
__global__ void k_keys(const double* __restrict__ sqd, const int* __restrict__ edges,
                       int E, int P, u64* __restrict__ keys) {
  int e = blockIdx.x * blockDim.x + threadIdx.x;
  if (e >= P) return;
  if (e < E) {
    double prio = sqd[edges[e]] + sqd[edges[E + e]];
    u64 bits = (u64)__double_as_longlong(prio);  // prio > 0 -> bits monotone
    keys[e] = (bits & ~0xFFFFull) | (u64)e;
  } else {
    keys[e] = ~0ull;
  }
}

// ---------------- single-block bitonic sort (P = pow2) ---------------------
__global__ void k_sort(u64* __restrict__ keys, int n) {
  int tid = threadIdx.x;
  int nt = blockDim.x;
  for (int k = 2; k <= n; k <<= 1) {
    for (int j = k >> 1; j > 0; j >>= 1) {
      for (int i = tid; i < n; i += nt) {
        int ixj = i ^ j;
        if (ixj > i) {
          u64 x = keys[i], y = keys[ixj];
          bool up = ((i & k) == 0);
          if (up ? (x > y) : (x < y)) { keys[i] = y; keys[ixj] = x; }
        }
      }
      __syncthreads();
    }
  }
}

// ---------------- gather sorted (v0,v1,elig) into one packed word ----------
__global__ void k_reorder(const u64* __restrict__ keys, const int* __restrict__ edges,
                          const unsigned char* __restrict__ elig, int E,
                          unsigned* __restrict__ packed) {
  int t = blockIdx.x * blockDim.x + threadIdx.x;
  if (t >= E) return;
  int eid = (int)(keys[t] & 0xFFFFull);
  unsigned v0 = (unsigned)edges[eid];
  unsigned v1 = (unsigned)edges[E + eid];
  unsigned el = (unsigned)elig[eid];
  packed[t] = v0 | (v1 << 14) | (el << 28);
}

// ---------------- sequential greedy decimation (single wave) ---------------
__global__ void __launch_bounds__(64)
k_decimate(int E, int V, int target, const unsigned* __restrict__ packed,
           const int* __restrict__ deg_g, unsigned short* __restrict__ nbr,
           int2* __restrict__ events, int* __restrict__ nev_out) {
  __shared__ unsigned short degs[MAXV];
  __shared__ unsigned short markA[MAXV];
  __shared__ unsigned short markB[MAXV];
  int lane = threadIdx.x;
  if (V > MAXV) return;
  for (int v = lane; v < V; v += 64) {
    degs[v] = (unsigned short)deg_g[v];
    markA[v] = 0;
    markB[v] = 0;
  }
  __syncthreads();

  int count = V, nev = 0;
  unsigned tag = 1;
  bool stop = false;
  u64 below = (lane == 0) ? 0ull : (~0ull >> (64 - lane));

  for (int base = 0; base < E && !stop; base += 64) {
    int t = base + lane;
    unsigned pk = (t < E) ? packed[t] : 0u;
    int mv0 = (int)(pk & 0x3FFFu);
    int mv1 = (int)((pk >> 14) & 0x3FFFu);
    bool cand = (t < E) && ((pk >> 28) & 1u) && (degs[mv0] > 0) && (degs[mv1] > 0);
    u64 cm = __ballot(cand);

    while (cm) {
      int idx = __builtin_ctzll(cm);
      cm &= cm - 1;
      unsigned pkc = __builtin_amdgcn_readlane(pk, idx);   // wave-uniform broadcast
      int cv0 = (int)(pkc & 0x3FFFu);
      int cv1 = (int)((pkc >> 14) & 0x3FFFu);

      // issue row gathers immediately; LDS deg check overlaps global latency
      unsigned aar = (unsigned)nbr[cv0 * CAP + lane];
      unsigned bbr = (unsigned)nbr[cv1 * CAP + lane];
      int d0 = degs[cv0], d1 = degs[cv1];
      if (d0 == 0 || d1 == 0) continue;   // died earlier in this batch

      bool valid0 = lane < d0;
      bool valid1 = lane < d1;

      // O(1) set membership via mark arrays (replaces O(d) shuffle loops)
      if (valid0) markA[aar] = (unsigned short)tag;
      if (valid1) markB[bbr] = (unsigned short)tag;
      asm volatile("s_waitcnt lgkmcnt(0)" ::: "memory");
      __builtin_amdgcn_sched_barrier(0);
      bool aInB = valid0 && (markB[aar] == (unsigned short)tag);
      bool bInA = valid1 && (markA[bbr] == (unsigned short)tag);
      asm volatile("s_waitcnt lgkmcnt(0)" ::: "memory");
      __builtin_amdgcn_sched_barrier(0);
      tag++;

      if (__popcll(__ballot(aInB)) != 2) continue;

      // ---- merge cv1 -> cv0 ----
      u64 keepMask = __ballot(valid0 && aar != (unsigned)cv1);
      u64 addMask  = __ballot(valid1 && bbr != (unsigned)cv0 && !bInA);
      int nKeep = __popcll(keepMask);
      int newd  = nKeep + __popcll(addMask);
      if (newd > CAP) newd = CAP;
      if (keepMask & (1ull << lane)) {
        int pos = __popcll(keepMask & below);
        nbr[cv0 * CAP + pos] = (unsigned short)aar;
      }
      if (addMask & (1ull << lane)) {
        int pos = nKeep + __popcll(addMask & below);
        if (pos < CAP) nbr[cv0 * CAP + pos] = (unsigned short)bbr;
      }

      // update each u in N(v1)\{v0}: replace v1 by v0, or drop v1 if v0 already there
      bool doU = valid1 && (bbr != (unsigned)cv0);
      if (doU) {
        int u = (int)bbr;
        int du = degs[u];
        const uint4* rowp = (const uint4*)(nbr + u * CAP);
        unsigned tg = (unsigned)cv1;
        int posv1 = -1;
        int nw = (du + 7) >> 3;
        for (int c = 0; c < nw; ++c) {
          uint4 w = rowp[c];
          int b8 = c << 3;
          if ((w.x & 0xFFFFu) == tg && b8 + 0 < du) posv1 = b8 + 0;
          if ((w.x >> 16)     == tg && b8 + 1 < du) posv1 = b8 + 1;
          if ((w.y & 0xFFFFu) == tg && b8 + 2 < du) posv1 = b8 + 2;
          if ((w.y >> 16)     == tg && b8 + 3 < du) posv1 = b8 + 3;
          if ((w.z & 0xFFFFu) == tg && b8 + 4 < du) posv1 = b8 + 4;
          if ((w.z >> 16)     == tg && b8 + 5 < du) posv1 = b8 + 5;
          if ((w.w & 0xFFFFu) == tg && b8 + 6 < du) posv1 = b8 + 6;
          if ((w.w >> 16)     == tg && b8 + 7 < du) posv1 = b8 + 7;
        }
        if (posv1 >= 0) {
          if (bInA) {  // v0 already a neighbor of u: remove v1
            nbr[u * CAP + posv1] = nbr[u * CAP + du - 1];
            degs[u] = (unsigned short)(du - 1);
          } else {
            nbr[u * CAP + posv1] = (unsigned short)cv0;
          }
        }
      }
      if (lane == 0) {
        degs[cv0] = (unsigned short)newd;
        degs[cv1] = 0;
        events[nev] = make_int2(cv0, cv1);
      }
      // make all global/LDS updates visible before next candidate's loads
      asm volatile("s_waitcnt vmcnt(0) lgkmcnt(0)" ::: "memory");
      __builtin_amdgcn_sched_barrier(0);
      nev++;
      count--;
      if (count <= target) { stop = true; break; }

      // prune candidates whose endpoints just died
      cm &= __ballot(cand && degs[mv0] > 0 && degs[mv1] > 0);
    }
  }
  if (lane == 0) nev_out[0] = nev;
}

// ---------------- reverse-replay: owner + weight per original vertex -------
__global__ void k_weights(const int2* __restrict__ events, const int* __restrict__ nev_p,
                          int V, int* __restrict__ own, float* __restrict__ wgt) {
  __shared__ int O[MAXV];
  __shared__ unsigned short H[MAXV];
  int tid = threadIdx.x;
  if (V > MAXV) return;
  for (int v = tid; v < V; v += blockDim.x) { O[v] = v; H[v] = 0; }
  __syncthreads();
  if (tid == 0) {
    int n = nev_p[0];
    for (int k = n - 1; k >= 0; --k) {
      int2 ev = events[k];
      int h = (int)H[ev.x] + 1;
      H[ev.x] = (unsigned short)h;
      H[ev.y] = (unsigned short)h;
      O[ev.y] = O[ev.x];
    }
  }
  __syncthreads();
  for (int v = tid; v < V; v += blockDim.x) {
    own[v] = O[v];
    wgt[v] = ldexpf(1.0f, -(int)H[v]);
  }
}

// ---------------- output ---------------------------------------------------
__global__ void k_zero(float4* __restrict__ out, int n4) {
  int i = blockIdx.x * blockDim.x + threadIdx.x;
  if (i < n4) out[i] = make_float4(0.f, 0.f, 0.f, 0.f);
}

__global__ void k_scatter(const float* __restrict__ img, const int* __restrict__ own,
                          const float* __restrict__ wgt, float* __restrict__ out, int V) {
  int v = blockIdx.x;
  if (v >= V) return;
  float w = wgt[v];
  int o = own[v];
  const float* src = img + (size_t)v * F_DIM;
  float* dst = out + (size_t)o * F_DIM;
  if (w == 1.0f) {
    for (int f = threadIdx.x; f < F_DIM; f += blockDim.x) dst[f] = src[f];
  } else {
    for (int f = threadIdx.x; f < F_DIM; f += blockDim.x) atomicAdd(&dst[f], w * src[f]);
  }
}

extern "C" void kernel_launch(void* const* d_in, const int* in_sizes, int n_in,
                              void* d_out, int out_size, void* d_ws, size_t ws_size,
                              hipStream_t stream) {
  const float* img  = (const float*)d_in[0];
  const int* edges  = (const int*)d_in[1];
  const float* vs   = (const float*)d_in[2];
  int V = in_sizes[2] / 2;
  int E = in_sizes[1] / 2;
  int P = 1; while (P < E) P <<= 1;

  char* wsp = (char*)d_ws;
  size_t off = 0;
  auto alloc = [&](size_t bytes) -> void* {
    void* p = (void*)(wsp + off);
    off = (off + bytes + 255) & ~(size_t)255;
    return p;
  };
  double* sqd          = (double*)alloc((size_t)V * 8);
  u64* keys            = (u64*)alloc((size_t)P * 8);
  int* deg             = (int*)alloc((size_t)V * 4);
  unsigned short* nbr  = (unsigned short*)alloc((size_t)V * CAP * 2);
  unsigned char* elig  = (unsigned char*)alloc((size_t)E);
  unsigned* packed     = (unsigned*)alloc((size_t)E * 4);
  int2* events         = (int2*)alloc((size_t)(V / 2 + 64) * 8);
  int* nev             = (int*)alloc(256);
  int* own             = (int*)alloc((size_t)V * 4);
  float* wgt           = (float*)alloc((size_t)V * 4);

  hipLaunchKernelGGL(k_sq, dim3(V), dim3(64), 0, stream, img, sqd, V);
  int mx = V > E ? V : E;
  hipLaunchKernelGGL(k_prep, dim3((mx + 255) / 256), dim3(256), 0, stream, vs, edges, V, E, deg, elig);
  hipLaunchKernelGGL(k_lists, dim3((E + 255) / 256), dim3(256), 0, stream, edges, E, deg, nbr);
  hipLaunchKernelGGL(k_keys, dim3((P + 255) / 256), dim3(256), 0, stream, sqd, edges, E, P, keys);
  hipLaunchKernelGGL(k_sort, dim3(1), dim3(1024), 0, stream, keys, P);
  hipLaunchKernelGGL(k_reorder, dim3((E + 255) / 256), dim3(256), 0, stream, keys, edges, elig, E, packed);
  hipLaunchKernelGGL(k_decimate, dim3(1), dim3(64), 0, stream,
                     E, V, V / 2, packed, deg, nbr, events, nev);
  hipLaunchKernelGGL(k_weights, dim3(1), dim3(256), 0, stream, events, nev, V, own, wgt);
  int n4 = (V * F_DIM) / 4;
  hipLaunchKernelGGL(k_zero, dim3((n4 + 255) / 256), dim3(256), 0, stream, (float4*)d_out, n4);
  hipLaunchKernelGGL(k_scatter, dim3(V), dim3(256), 0, stream, img, own, wgt, (float*)d_out, V);
}